// Round 1
// 1133.680 us; speedup vs baseline: 1.0167x; 1.0167x over previous
//
#include <hip/hip_runtime.h>
#include <hip/hip_bf16.h>
#include <stdint.h>

#define NN 12288
#define INF_ 256
#define OUTF 128
#define SLOPE 0.2f
#define JSPLIT 8                 // k3 j-dimension split: 96 c-chunks -> 12 per block
#define CPB (NN/128/JSPLIT)      // c-chunks per block = 12

typedef __bf16 bf16x8 __attribute__((ext_vector_type(8)));
typedef float f32x16 __attribute__((ext_vector_type(16)));
typedef float f32x4 __attribute__((ext_vector_type(4)));
typedef uint32_t u32x4 __attribute__((ext_vector_type(4)));

union BFU { u32x4 u; bf16x8 b; };

__device__ __forceinline__ float bflo(uint32_t u){ return __uint_as_float(u << 16); }
__device__ __forceinline__ float bfhi(uint32_t u){ return __uint_as_float(u & 0xffff0000u); }
__device__ __forceinline__ uint32_t f2bf(float f){
    union { __bf16 b; uint16_t s; } u; u.b = (__bf16)f; return (uint32_t)u.s;
}
__device__ __forceinline__ void unpack8(u32x4 u, float* f){
    f[0]=bflo(u.x); f[1]=bfhi(u.x); f[2]=bflo(u.y); f[3]=bfhi(u.y);
    f[4]=bflo(u.z); f[5]=bfhi(u.z); f[6]=bflo(u.w); f[7]=bfhi(u.w);
}

// ---------------- K0: input dtype detector --------------------------------
__global__ __launch_bounds__(256) void k0_detect(const uint32_t* __restrict__ hw,
                                                 uint32_t* __restrict__ flag)
{
    __shared__ int cnt[4];
    int t = threadIdx.x;
    uint32_t w = hw[t];
    uint32_t e = (w >> 7) & 0xffu;           // lo-bf16 exponent field
    int s = (e >= 110u && e <= 140u) ? 1 : 0;
    #pragma unroll
    for (int mm=1;mm<64;mm<<=1) s += __shfl_xor(s,mm,64);
    if ((t&63)==0) cnt[t>>6]=s;
    __syncthreads();
    if (t==0) flag[0] = ((cnt[0]+cnt[1]+cnt[2]+cnt[3]) < 128) ? 1u : 0u;
}

// ---------------- K1: h_t = h@W, src/tgt, packed h_t^T (B-frag layout) ----
__global__ __launch_bounds__(256) void k1_ht(
    const void* __restrict__ h, const void* __restrict__ Wp,
    const void* __restrict__ a, const uint32_t* __restrict__ flagp,
    uint16_t* __restrict__ packed, float* __restrict__ src, float* __restrict__ tgt)
{
    __shared__ __align__(16) uint16_t tile[16*128];
    int t = threadIdx.x;
    int rloc = t >> 4;
    int row = blockIdx.x*16 + rloc;
    int f0 = (t & 15) * 8;
    bool f32in = flagp[0] != 0u;

    float acc[8];
    #pragma unroll
    for (int c=0;c<8;c++) acc[c]=0.f;
    float a1f[8], a2f[8];

    if (f32in){
        const float* hrow = (const float*)h + (size_t)row*INF_;
        const float* Wf   = (const float*)Wp;
        for (int k=0;k<INF_;k+=8){
            float hv[8];
            *(f32x4*)&hv[0] = *(const f32x4*)(hrow + k);
            *(f32x4*)&hv[4] = *(const f32x4*)(hrow + k + 4);
            #pragma unroll
            for (int i=0;i<8;i++){
                const float* w0 = Wf + (size_t)(k+i)*OUTF + f0;
                float wf[8];
                *(f32x4*)&wf[0] = *(const f32x4*)w0;
                *(f32x4*)&wf[4] = *(const f32x4*)(w0+4);
                #pragma unroll
                for (int c=0;c<8;c++) acc[c] = fmaf(hv[i], wf[c], acc[c]);
            }
        }
        const float* af = (const float*)a;
        *(f32x4*)&a1f[0] = *(const f32x4*)(af + f0);
        *(f32x4*)&a1f[4] = *(const f32x4*)(af + f0 + 4);
        *(f32x4*)&a2f[0] = *(const f32x4*)(af + OUTF + f0);
        *(f32x4*)&a2f[4] = *(const f32x4*)(af + OUTF + f0 + 4);
    } else {
        const uint16_t* hrow = (const uint16_t*)h + (size_t)row*INF_;
        const uint16_t* W16  = (const uint16_t*)Wp;
        for (int k=0;k<INF_;k+=8){
            u32x4 hu = *(const u32x4*)(hrow + k);
            float hv[8]; unpack8(hu,hv);
            #pragma unroll
            for (int i=0;i<8;i++){
                u32x4 wu = *(const u32x4*)(W16 + (size_t)(k+i)*OUTF + f0);
                float wf[8]; unpack8(wu,wf);
                #pragma unroll
                for (int c=0;c<8;c++) acc[c] = fmaf(hv[i], wf[c], acc[c]);
            }
        }
        const uint16_t* a16 = (const uint16_t*)a;
        u32x4 a1u = *(const u32x4*)(a16 + f0);
        u32x4 a2u = *(const u32x4*)(a16 + OUTF + f0);
        unpack8(a1u,a1f); unpack8(a2u,a2f);
    }

    float p1=0.f, p2=0.f;
    #pragma unroll
    for (int c=0;c<8;c++){ p1 = fmaf(acc[c],a1f[c],p1); p2 = fmaf(acc[c],a2f[c],p2); }
    #pragma unroll
    for (int mm=1;mm<16;mm<<=1){ p1 += __shfl_xor(p1,mm,64); p2 += __shfl_xor(p2,mm,64); }
    if ((t&15)==0){ src[row]=p1; tgt[row]=p2; }

    uint32_t q0 = f2bf(acc[0]) | (f2bf(acc[1])<<16);
    uint32_t q1 = f2bf(acc[2]) | (f2bf(acc[3])<<16);
    uint32_t q2 = f2bf(acc[4]) | (f2bf(acc[5])<<16);
    uint32_t q3 = f2bf(acc[6]) | (f2bf(acc[7])<<16);
    u32x4 pk = {q0,q1,q2,q3};
    *(u32x4*)&tile[rloc*128 + f0] = pk;
    __syncthreads();
    int n = t >> 1, kb = (t & 1) * 8;
    uint32_t g0 = (uint32_t)tile[(kb+0)*128+n] | ((uint32_t)tile[(kb+1)*128+n]<<16);
    uint32_t g1 = (uint32_t)tile[(kb+2)*128+n] | ((uint32_t)tile[(kb+3)*128+n]<<16);
    uint32_t g2 = (uint32_t)tile[(kb+4)*128+n] | ((uint32_t)tile[(kb+5)*128+n]<<16);
    uint32_t g3 = (uint32_t)tile[(kb+6)*128+n] | ((uint32_t)tile[(kb+7)*128+n]<<16);
    u32x4 ov = {g0,g1,g2,g3};
    *(u32x4*)(packed + (size_t)blockIdx.x*2048 + t*8) = ov;
}

// ---------------- K1b: max over tgt --------------------------------------
__global__ __launch_bounds__(256) void k1b_max(const float* __restrict__ tgt,
                                               float* __restrict__ maxtgt)
{
    __shared__ float red[4];
    int t = threadIdx.x;
    float m = -3.4e38f;
    for (int j=t; j<NN; j+=256) m = fmaxf(m, tgt[j]);
    #pragma unroll
    for (int mm=1;mm<64;mm<<=1) m = fmaxf(m, __shfl_xor(m,mm,64));
    if ((t&63)==0) red[t>>6]=m;
    __syncthreads();
    if (t==0) maxtgt[0] = fmaxf(fmaxf(red[0],red[1]), fmaxf(red[2],red[3]));
}

// ---------------- K1c: zero h_prime f32 accumulator -----------------------
__global__ __launch_bounds__(256) void k1c_zero(float* __restrict__ hp)
{
    int i = blockIdx.x*256 + threadIdx.x;
    f32x4 z = {0.f,0.f,0.f,0.f};
    *(f32x4*)(hp + (size_t)i*4) = z;
}

// ---------------- K2: adj -> bitmask, row sums ----------------------------
__global__ __launch_bounds__(256) void k2_mask(
    const int* __restrict__ adj, const float* __restrict__ src,
    const float* __restrict__ maxtgt, const float* __restrict__ tgt,
    uint32_t* __restrict__ bm, float* __restrict__ Mrow, float* __restrict__ Srow)
{
    __shared__ float ls[4];
    int row = blockIdx.x, t = threadIdx.x;
    float sr = src[row];
    float e0 = sr + maxtgt[0];
    float M  = fmaxf(e0, SLOPE*e0);
    const u32x4* arow = (const u32x4*)(adj + (size_t)row*NN);
    uint32_t* bmrow = bm + (size_t)row*384;
    float sum = 0.f;
    #pragma unroll
    for (int jb=0;jb<12;jb++){
        int j0 = jb*1024 + t*4;
        u32x4 a4 = __builtin_nontemporal_load(arow + jb*256 + t);
        float4 t4 = *(const float4*)(tgt + j0);
        uint32_t nib = (a4.x!=0u) | ((a4.y!=0u)<<1) | ((a4.z!=0u)<<2) | ((a4.w!=0u)<<3);
        float ev, lv, pv;
        ev = sr + t4.x; lv = fmaxf(ev, SLOPE*ev); pv = __expf(lv - M); sum += (nib&1u)     ? pv : 0.f;
        ev = sr + t4.y; lv = fmaxf(ev, SLOPE*ev); pv = __expf(lv - M); sum += ((nib>>1)&1u)? pv : 0.f;
        ev = sr + t4.z; lv = fmaxf(ev, SLOPE*ev); pv = __expf(lv - M); sum += ((nib>>2)&1u)? pv : 0.f;
        ev = sr + t4.w; lv = fmaxf(ev, SLOPE*ev); pv = __expf(lv - M); sum += ((nib>>3)&1u)? pv : 0.f;
        uint32_t wv = nib << ((t&7)*4);
        wv |= __shfl_xor(wv,1,64); wv |= __shfl_xor(wv,2,64); wv |= __shfl_xor(wv,4,64);
        if ((t&7)==0) __builtin_nontemporal_store(wv, bmrow + jb*32 + (t>>3));
    }
    #pragma unroll
    for (int mm=1;mm<64;mm<<=1) sum += __shfl_xor(sum,mm,64);
    if ((t&63)==0) ls[t>>6]=sum;
    __syncthreads();
    if (t==0){ Srow[row] = ls[0]+ls[1]+ls[2]+ls[3]; Mrow[row] = M; }
}

// ---------------- K3: attention write + PV MFMA (j-split for occupancy) ---
// R1 change: grid is now (NN/32, JSPLIT). blockIdx.y selects a 12-chunk
// j-slice; each block accumulates a PARTIAL 32x128 h_prime tile and
// atomicAdds it into the f32 workspace hp. Raises occupancy from
// 1.5 blocks/CU (latency-exposed serial c-loop) to 8 blocks/CU.
__global__ __launch_bounds__(256) void k3_pv(
    const uint32_t* __restrict__ bm, const float* __restrict__ tgt,
    const float* __restrict__ src, const float* __restrict__ Mrow,
    const float* __restrict__ Srow, const uint16_t* __restrict__ packed,
    const uint32_t* __restrict__ flagp, float* __restrict__ hp,
    void* __restrict__ out)
{
    __shared__ __align__(16) uint16_t P[32*136];   // pitch 136 bf16 breaks bank conflicts
    int t = threadIdx.x;
    int lane = t & 63, wv = t >> 6;
    int r0 = blockIdx.x * 32;
    int rr0 = t >> 4;                // 0..15 (thread also does rr0+16)
    int jg  = t & 15; int jl0 = jg*8;
    int n0 = wv*32;
    int m = lane & 31, kq = lane >> 5;
    bool f32out = flagp[0] != 0u;

    uint16_t* hprime16 = (uint16_t*)out;
    uint16_t* attn16   = hprime16 + (size_t)NN*OUTF;
    float*    hprimef  = (float*)out;
    float*    attnf    = hprimef + (size_t)NN*OUTF;

    float s0 = src[r0+rr0],      s1 = src[r0+rr0+16];
    float M0 = Mrow[r0+rr0],     M1 = Mrow[r0+rr0+16];
    float S0 = Srow[r0+rr0],     S1 = Srow[r0+rr0+16];
    float inv0 = S0>0.f ? 1.f/S0 : 0.f;  float fb0 = S0>0.f ? 0.f : 1.f/NN;
    float inv1 = S1>0.f ? 1.f/S1 : 0.f;  float fb1 = S1>0.f ? 0.f : 1.f/NN;

    f32x16 acc;
    #pragma unroll
    for (int i=0;i<16;i++) acc[i]=0.f;

    int cs = blockIdx.y * CPB;
    for (int c=cs; c<cs+CPB; c++){
        int jbase = c*128;
        float tg[8];
        *(f32x4*)&tg[0] = *(const f32x4*)(tgt + jbase + jl0);
        *(f32x4*)&tg[4] = *(const f32x4*)(tgt + jbase + jl0 + 4);
        #pragma unroll
        for (int hh=0;hh<2;hh++){
            int rr = rr0 + hh*16;
            uint32_t word = bm[(size_t)(r0+rr)*384 + (c<<2) + (jg>>2)];
            uint32_t byt  = (word >> ((jg&3)*8)) & 0xffu;
            float sv = hh? s1:s0, Mv = hh? M1:M0, iv = hh? inv1:inv0, fv = hh? fb1:fb0;
            uint32_t pk[4];
            float pf[8];
            #pragma unroll
            for (int i=0;i<4;i++){
                float ea = sv + tg[2*i],   eb = sv + tg[2*i+1];
                float la = fmaxf(ea, SLOPE*ea), lb = fmaxf(eb, SLOPE*eb);
                float pa = ((byt>>(2*i))&1u)   ? __expf(la-Mv)*iv : fv;
                float pb = ((byt>>(2*i+1))&1u) ? __expf(lb-Mv)*iv : fv;
                pk[i] = f2bf(pa) | (f2bf(pb)<<16);
                pf[2*i] = pa; pf[2*i+1] = pb;
            }
            u32x4 pv4 = {pk[0],pk[1],pk[2],pk[3]};
            if (f32out){
                f32x4 fa = {pf[0],pf[1],pf[2],pf[3]};
                f32x4 fb = {pf[4],pf[5],pf[6],pf[7]};
                float* dst = attnf + (size_t)(r0+rr)*NN + jbase + jl0;
                __builtin_nontemporal_store(fa, (f32x4*)dst);
                __builtin_nontemporal_store(fb, (f32x4*)(dst+4));
            } else {
                __builtin_nontemporal_store(pv4,
                    (u32x4*)(attn16 + (size_t)(r0+rr)*NN + jbase + jl0));
            }
            *(u32x4*)&P[rr*136 + jl0] = pv4;
        }
        __syncthreads();
        #pragma unroll
        for (int kt=0;kt<8;kt++){
            BFU A; A.u = *(const u32x4*)&P[m*136 + (kt<<4) + (kq<<3)];
            BFU B; B.u = *(const u32x4*)(packed +
                        (((size_t)(c*8+kt))<<11) + ((size_t)(n0+m)<<4) + (kq<<3));
            acc = __builtin_amdgcn_mfma_f32_32x32x16_bf16(A.b, B.b, acc, 0, 0, 0);
        }
        __syncthreads();
    }
    // D layout (32x32): col = lane&31, row = (reg&3) + 8*(reg>>2) + 4*(lane>>5)
    // Partial over this block's j-slice -> accumulate into hp (f32).
    #pragma unroll
    for (int r=0;r<16;r++){
        int orow = (r&3) + 8*(r>>2) + 4*kq;
        atomicAdd(&hp[(size_t)(r0+orow)*OUTF + n0 + m], acc[r]);
    }
}

// ---------------- K4: finalize h_prime (copy/convert from hp) -------------
__global__ __launch_bounds__(256) void k4_fin(const float* __restrict__ hp,
    const uint32_t* __restrict__ flagp, void* __restrict__ out)
{
    int t = blockIdx.x*256 + threadIdx.x;   // 768*256 threads, 8 elems each
    size_t base = (size_t)t*8;
    bool f32out = flagp[0] != 0u;
    f32x4 v0 = *(const f32x4*)(hp + base);
    f32x4 v1 = *(const f32x4*)(hp + base + 4);
    if (f32out){
        float* o = (float*)out;
        *(f32x4*)(o + base)     = v0;
        *(f32x4*)(o + base + 4) = v1;
    } else {
        uint32_t q0 = f2bf(v0.x) | (f2bf(v0.y)<<16);
        uint32_t q1 = f2bf(v0.z) | (f2bf(v0.w)<<16);
        uint32_t q2 = f2bf(v1.x) | (f2bf(v1.y)<<16);
        uint32_t q3 = f2bf(v1.z) | (f2bf(v1.w)<<16);
        u32x4 pk = {q0,q1,q2,q3};
        *(u32x4*)((uint16_t*)out + base) = pk;
    }
}

// ---------------- launch ---------------------------------------------------
extern "C" void kernel_launch(void* const* d_in, const int* in_sizes, int n_in,
                              void* d_out, int out_size, void* d_ws, size_t ws_size,
                              hipStream_t stream)
{
    const void* h  = d_in[0];
    const int*  adj= (const int*)d_in[1];
    const void* W  = d_in[2];
    const void* a  = d_in[3];

    char* ws = (char*)d_ws;
    uint16_t* packed = (uint16_t*)ws;                    // 3,145,728 B
    float* src    = (float*)(ws + 3145728);              // 49,152 B
    float* tgt    = (float*)(ws + 3194880);              // 49,152 B
    float* Mrow   = (float*)(ws + 3244032);              // 49,152 B
    float* Srow   = (float*)(ws + 3293184);              // 49,152 B
    float* maxtgt = (float*)(ws + 3342336);              // 64 B
    uint32_t* flag= (uint32_t*)(ws + 3342400);           // 64 B
    uint32_t* bm  = (uint32_t*)(ws + 3342464);           // 18,874,368 B
    float* hp     = (float*)(ws + 22216832);             // 6,291,456 B (total ~28.5 MiB)

    k0_detect<<<dim3(1),    dim3(256), 0, stream>>>((const uint32_t*)h, flag);
    k1_ht    <<<dim3(NN/16),dim3(256), 0, stream>>>(h, W, a, flag, packed, src, tgt);
    k1b_max  <<<dim3(1),    dim3(256), 0, stream>>>(tgt, maxtgt);
    k1c_zero <<<dim3(NN*OUTF/1024), dim3(256), 0, stream>>>(hp);
    k2_mask  <<<dim3(NN),   dim3(256), 0, stream>>>(adj, src, maxtgt, tgt, bm, Mrow, Srow);
    k3_pv    <<<dim3(NN/32, JSPLIT), dim3(256), 0, stream>>>(bm, tgt, src, Mrow, Srow,
                                                             packed, flag, hp, d_out);
    k4_fin   <<<dim3(NN*OUTF/2048), dim3(256), 0, stream>>>(hp, flag, d_out);
}

// Round 2
// 1132.758 us; speedup vs baseline: 1.0175x; 1.0008x over previous
//
#include <hip/hip_runtime.h>
#include <hip/hip_bf16.h>
#include <stdint.h>

#define NN 12288
#define INF_ 256
#define OUTF 128
#define SLOPE 0.2f
#define JSPLIT 4                 // k3 j-dimension split: 96 c-chunks -> 24 per block
#define CPB (NN/128/JSPLIT)      // c-chunks per block = 24

typedef __bf16 bf16x8 __attribute__((ext_vector_type(8)));
typedef float f32x16 __attribute__((ext_vector_type(16)));
typedef float f32x4 __attribute__((ext_vector_type(4)));
typedef uint32_t u32x4 __attribute__((ext_vector_type(4)));

union BFU { u32x4 u; bf16x8 b; };

__device__ __forceinline__ float bflo(uint32_t u){ return __uint_as_float(u << 16); }
__device__ __forceinline__ float bfhi(uint32_t u){ return __uint_as_float(u & 0xffff0000u); }
__device__ __forceinline__ uint32_t f2bf(float f){
    union { __bf16 b; uint16_t s; } u; u.b = (__bf16)f; return (uint32_t)u.s;
}
__device__ __forceinline__ void unpack8(u32x4 u, float* f){
    f[0]=bflo(u.x); f[1]=bfhi(u.x); f[2]=bflo(u.y); f[3]=bfhi(u.y);
    f[4]=bflo(u.z); f[5]=bfhi(u.z); f[6]=bflo(u.w); f[7]=bfhi(u.w);
}

// Monotone uint encoding of float for atomicMax (orders like f32 compare).
__device__ __forceinline__ uint32_t fenc(float f){
    uint32_t b = __float_as_uint(f);
    return b ^ ((b & 0x80000000u) ? 0xFFFFFFFFu : 0x80000000u);
}
__device__ __forceinline__ float fdec(uint32_t e){
    uint32_t b = e ^ ((e & 0x80000000u) ? 0x80000000u : 0xFFFFFFFFu);
    return __uint_as_float(b);
}

// In-block input dtype detect (replaces k0): reads first 256 words of h.
// bf16 inputs -> low 16 bits are real bf16 normals (exponent in [110,140]);
// f32 inputs -> low bits are mantissa noise (~9% hit rate). Returns f32in.
__device__ __forceinline__ bool detect_f32(const uint32_t* hw, int t, int* cnt){
    uint32_t w = hw[t & 255];
    uint32_t e = (w >> 7) & 0xffu;
    int s = (e >= 110u && e <= 140u) ? 1 : 0;
    #pragma unroll
    for (int mm=1;mm<64;mm<<=1) s += __shfl_xor(s,mm,64);
    if ((t&63)==0) cnt[t>>6]=s;
    __syncthreads();
    return (cnt[0]+cnt[1]+cnt[2]+cnt[3]) < 128;
}

// ---------------- K1: h_t = h@W, src/tgt(+atomic max), packed h_t^T -------
__global__ __launch_bounds__(256) void k1_ht(
    const void* __restrict__ h, const void* __restrict__ Wp,
    const void* __restrict__ a,
    uint16_t* __restrict__ packed, float* __restrict__ src, float* __restrict__ tgt,
    uint32_t* __restrict__ maxtgt)
{
    __shared__ __align__(16) uint16_t tile[16*128];
    __shared__ int cnt[4];
    __shared__ float wmax[4];
    int t = threadIdx.x;
    bool f32in = detect_f32((const uint32_t*)h, t, cnt);

    int rloc = t >> 4;
    int row = blockIdx.x*16 + rloc;
    int f0 = (t & 15) * 8;

    float acc[8];
    #pragma unroll
    for (int c=0;c<8;c++) acc[c]=0.f;
    float a1f[8], a2f[8];

    if (f32in){
        const float* hrow = (const float*)h + (size_t)row*INF_;
        const float* Wf   = (const float*)Wp;
        for (int k=0;k<INF_;k+=8){
            float hv[8];
            *(f32x4*)&hv[0] = *(const f32x4*)(hrow + k);
            *(f32x4*)&hv[4] = *(const f32x4*)(hrow + k + 4);
            #pragma unroll
            for (int i=0;i<8;i++){
                const float* w0 = Wf + (size_t)(k+i)*OUTF + f0;
                float wf[8];
                *(f32x4*)&wf[0] = *(const f32x4*)w0;
                *(f32x4*)&wf[4] = *(const f32x4*)(w0+4);
                #pragma unroll
                for (int c=0;c<8;c++) acc[c] = fmaf(hv[i], wf[c], acc[c]);
            }
        }
        const float* af = (const float*)a;
        *(f32x4*)&a1f[0] = *(const f32x4*)(af + f0);
        *(f32x4*)&a1f[4] = *(const f32x4*)(af + f0 + 4);
        *(f32x4*)&a2f[0] = *(const f32x4*)(af + OUTF + f0);
        *(f32x4*)&a2f[4] = *(const f32x4*)(af + OUTF + f0 + 4);
    } else {
        const uint16_t* hrow = (const uint16_t*)h + (size_t)row*INF_;
        const uint16_t* W16  = (const uint16_t*)Wp;
        for (int k=0;k<INF_;k+=8){
            u32x4 hu = *(const u32x4*)(hrow + k);
            float hv[8]; unpack8(hu,hv);
            #pragma unroll
            for (int i=0;i<8;i++){
                u32x4 wu = *(const u32x4*)(W16 + (size_t)(k+i)*OUTF + f0);
                float wf[8]; unpack8(wu,wf);
                #pragma unroll
                for (int c=0;c<8;c++) acc[c] = fmaf(hv[i], wf[c], acc[c]);
            }
        }
        const uint16_t* a16 = (const uint16_t*)a;
        u32x4 a1u = *(const u32x4*)(a16 + f0);
        u32x4 a2u = *(const u32x4*)(a16 + OUTF + f0);
        unpack8(a1u,a1f); unpack8(a2u,a2f);
    }

    float p1=0.f, p2=0.f;
    #pragma unroll
    for (int c=0;c<8;c++){ p1 = fmaf(acc[c],a1f[c],p1); p2 = fmaf(acc[c],a2f[c],p2); }
    #pragma unroll
    for (int mm=1;mm<16;mm<<=1){ p1 += __shfl_xor(p1,mm,64); p2 += __shfl_xor(p2,mm,64); }
    if ((t&15)==0){ src[row]=p1; tgt[row]=p2; }

    // wave max of the 4 row-tgt values held by this wave (all lanes have p2)
    float bmx = p2;
    #pragma unroll
    for (int mm=16;mm<64;mm<<=1) bmx = fmaxf(bmx, __shfl_xor(bmx,mm,64));
    if ((t&63)==0) wmax[t>>6] = bmx;

    uint32_t q0 = f2bf(acc[0]) | (f2bf(acc[1])<<16);
    uint32_t q1 = f2bf(acc[2]) | (f2bf(acc[3])<<16);
    uint32_t q2 = f2bf(acc[4]) | (f2bf(acc[5])<<16);
    uint32_t q3 = f2bf(acc[6]) | (f2bf(acc[7])<<16);
    u32x4 pk = {q0,q1,q2,q3};
    *(u32x4*)&tile[rloc*128 + f0] = pk;
    __syncthreads();
    if (t==0){
        float m4 = fmaxf(fmaxf(wmax[0],wmax[1]), fmaxf(wmax[2],wmax[3]));
        atomicMax(maxtgt, fenc(m4));
    }
    int n = t >> 1, kb = (t & 1) * 8;
    uint32_t g0 = (uint32_t)tile[(kb+0)*128+n] | ((uint32_t)tile[(kb+1)*128+n]<<16);
    uint32_t g1 = (uint32_t)tile[(kb+2)*128+n] | ((uint32_t)tile[(kb+3)*128+n]<<16);
    uint32_t g2 = (uint32_t)tile[(kb+4)*128+n] | ((uint32_t)tile[(kb+5)*128+n]<<16);
    uint32_t g3 = (uint32_t)tile[(kb+6)*128+n] | ((uint32_t)tile[(kb+7)*128+n]<<16);
    u32x4 ov = {g0,g1,g2,g3};
    *(u32x4*)(packed + (size_t)blockIdx.x*2048 + t*8) = ov;
}

// ---------------- K2: adj -> bitmask, row sums ----------------------------
__global__ __launch_bounds__(256) void k2_mask(
    const int* __restrict__ adj, const float* __restrict__ src,
    const uint32_t* __restrict__ maxtgt, const float* __restrict__ tgt,
    uint32_t* __restrict__ bm, float* __restrict__ Mrow, float* __restrict__ Srow)
{
    __shared__ float ls[4];
    int row = blockIdx.x, t = threadIdx.x;
    float sr = src[row];
    float e0 = sr + fdec(maxtgt[0]);
    float M  = fmaxf(e0, SLOPE*e0);           // leaky-relu of upper bound on row scores
    const u32x4* arow = (const u32x4*)(adj + (size_t)row*NN);
    uint32_t* bmrow = bm + (size_t)row*384;
    float sum = 0.f;
    #pragma unroll
    for (int jb=0;jb<12;jb++){
        int j0 = jb*1024 + t*4;
        u32x4 a4 = __builtin_nontemporal_load(arow + jb*256 + t);
        float4 t4 = *(const float4*)(tgt + j0);
        uint32_t nib = (a4.x!=0u) | ((a4.y!=0u)<<1) | ((a4.z!=0u)<<2) | ((a4.w!=0u)<<3);
        float ev, lv, pv;
        ev = sr + t4.x; lv = fmaxf(ev, SLOPE*ev); pv = __expf(lv - M); sum += (nib&1u)     ? pv : 0.f;
        ev = sr + t4.y; lv = fmaxf(ev, SLOPE*ev); pv = __expf(lv - M); sum += ((nib>>1)&1u)? pv : 0.f;
        ev = sr + t4.z; lv = fmaxf(ev, SLOPE*ev); pv = __expf(lv - M); sum += ((nib>>2)&1u)? pv : 0.f;
        ev = sr + t4.w; lv = fmaxf(ev, SLOPE*ev); pv = __expf(lv - M); sum += ((nib>>3)&1u)? pv : 0.f;
        uint32_t wv = nib << ((t&7)*4);
        wv |= __shfl_xor(wv,1,64); wv |= __shfl_xor(wv,2,64); wv |= __shfl_xor(wv,4,64);
        if ((t&7)==0) __builtin_nontemporal_store(wv, bmrow + jb*32 + (t>>3));
    }
    #pragma unroll
    for (int mm=1;mm<64;mm<<=1) sum += __shfl_xor(sum,mm,64);
    if ((t&63)==0) ls[t>>6]=sum;
    __syncthreads();
    if (t==0){ Srow[row] = ls[0]+ls[1]+ls[2]+ls[3]; Mrow[row] = M; }
}

// ---------------- K3: attention write + PV MFMA (j-split, partial tiles) --
__global__ __launch_bounds__(256) void k3_pv(
    const uint32_t* __restrict__ bm, const float* __restrict__ tgt,
    const float* __restrict__ src, const float* __restrict__ Mrow,
    const float* __restrict__ Srow, const uint16_t* __restrict__ packed,
    const void* __restrict__ h, float* __restrict__ hp,
    void* __restrict__ out)
{
    __shared__ __align__(16) uint16_t P[32*136];   // pitch 136 bf16 breaks bank conflicts
    __shared__ int cnt[4];
    int t = threadIdx.x;
    bool f32out = detect_f32((const uint32_t*)h, t, cnt);

    int lane = t & 63, wv = t >> 6;
    int r0 = blockIdx.x * 32;
    int rr0 = t >> 4;                // 0..15 (thread also does rr0+16)
    int jg  = t & 15; int jl0 = jg*8;
    int n0 = wv*32;
    int m = lane & 31, kq = lane >> 5;

    uint16_t* attn16 = (uint16_t*)out + (size_t)NN*OUTF;
    float*    attnf  = (float*)out + (size_t)NN*OUTF;

    float s0 = src[r0+rr0],      s1 = src[r0+rr0+16];
    float M0 = Mrow[r0+rr0],     M1 = Mrow[r0+rr0+16];
    float S0 = Srow[r0+rr0],     S1 = Srow[r0+rr0+16];
    float inv0 = S0>0.f ? 1.f/S0 : 0.f;  float fb0 = S0>0.f ? 0.f : 1.f/NN;
    float inv1 = S1>0.f ? 1.f/S1 : 0.f;  float fb1 = S1>0.f ? 0.f : 1.f/NN;

    f32x16 acc;
    #pragma unroll
    for (int i=0;i<16;i++) acc[i]=0.f;

    int cs = blockIdx.y * CPB;
    for (int c=cs; c<cs+CPB; c++){
        int jbase = c*128;
        float tg[8];
        *(f32x4*)&tg[0] = *(const f32x4*)(tgt + jbase + jl0);
        *(f32x4*)&tg[4] = *(const f32x4*)(tgt + jbase + jl0 + 4);
        #pragma unroll
        for (int hh=0;hh<2;hh++){
            int rr = rr0 + hh*16;
            uint32_t word = bm[(size_t)(r0+rr)*384 + (c<<2) + (jg>>2)];
            uint32_t byt  = (word >> ((jg&3)*8)) & 0xffu;
            float sv = hh? s1:s0, Mv = hh? M1:M0, iv = hh? inv1:inv0, fv = hh? fb1:fb0;
            uint32_t pk[4];
            float pf[8];
            #pragma unroll
            for (int i=0;i<4;i++){
                float ea = sv + tg[2*i],   eb = sv + tg[2*i+1];
                float la = fmaxf(ea, SLOPE*ea), lb = fmaxf(eb, SLOPE*eb);
                float pa = ((byt>>(2*i))&1u)   ? __expf(la-Mv)*iv : fv;
                float pb = ((byt>>(2*i+1))&1u) ? __expf(lb-Mv)*iv : fv;
                pk[i] = f2bf(pa) | (f2bf(pb)<<16);
                pf[2*i] = pa; pf[2*i+1] = pb;
            }
            u32x4 pv4 = {pk[0],pk[1],pk[2],pk[3]};
            if (f32out){
                f32x4 fa = {pf[0],pf[1],pf[2],pf[3]};
                f32x4 fb = {pf[4],pf[5],pf[6],pf[7]};
                float* dst = attnf + (size_t)(r0+rr)*NN + jbase + jl0;
                __builtin_nontemporal_store(fa, (f32x4*)dst);
                __builtin_nontemporal_store(fb, (f32x4*)(dst+4));
            } else {
                __builtin_nontemporal_store(pv4,
                    (u32x4*)(attn16 + (size_t)(r0+rr)*NN + jbase + jl0));
            }
            *(u32x4*)&P[rr*136 + jl0] = pv4;
        }
        __syncthreads();
        #pragma unroll
        for (int kt=0;kt<8;kt++){
            BFU A; A.u = *(const u32x4*)&P[m*136 + (kt<<4) + (kq<<3)];
            BFU B; B.u = *(const u32x4*)(packed +
                        (((size_t)(c*8+kt))<<11) + ((size_t)(n0+m)<<4) + (kq<<3));
            acc = __builtin_amdgcn_mfma_f32_32x32x16_bf16(A.b, B.b, acc, 0, 0, 0);
        }
        __syncthreads();
    }
    // D layout (32x32): col = lane&31, row = (reg&3) + 8*(reg>>2) + 4*(lane>>5)
    // Partial over this block's j-slice -> per-y partial tile (no atomics).
    float* hpp = hp + (size_t)blockIdx.y * ((size_t)NN*OUTF);
    #pragma unroll
    for (int r=0;r<16;r++){
        int orow = (r&3) + 8*(r>>2) + 4*kq;
        hpp[(size_t)(r0+orow)*OUTF + n0 + m] = acc[r];
    }
}

// ---------------- K4: reduce partials -> h_prime --------------------------
__global__ __launch_bounds__(256) void k4_fin(const float* __restrict__ hp,
    const void* __restrict__ h, void* __restrict__ out)
{
    __shared__ int cnt[4];
    int t = threadIdx.x;
    bool f32out = detect_f32((const uint32_t*)h, t, cnt);
    size_t base = ((size_t)blockIdx.x*256 + t)*8;
    f32x4 v0 = {0.f,0.f,0.f,0.f}, v1 = {0.f,0.f,0.f,0.f};
    #pragma unroll
    for (int y=0;y<JSPLIT;y++){
        const float* p = hp + (size_t)y*((size_t)NN*OUTF) + base;
        f32x4 a0 = *(const f32x4*)p;
        f32x4 a1 = *(const f32x4*)(p+4);
        v0 += a0; v1 += a1;
    }
    if (f32out){
        float* o = (float*)out;
        *(f32x4*)(o + base)     = v0;
        *(f32x4*)(o + base + 4) = v1;
    } else {
        uint32_t q0 = f2bf(v0.x) | (f2bf(v0.y)<<16);
        uint32_t q1 = f2bf(v0.z) | (f2bf(v0.w)<<16);
        uint32_t q2 = f2bf(v1.x) | (f2bf(v1.y)<<16);
        uint32_t q3 = f2bf(v1.z) | (f2bf(v1.w)<<16);
        u32x4 pk = {q0,q1,q2,q3};
        *(u32x4*)((uint16_t*)out + base) = pk;
    }
}

// ---------------- launch ---------------------------------------------------
extern "C" void kernel_launch(void* const* d_in, const int* in_sizes, int n_in,
                              void* d_out, int out_size, void* d_ws, size_t ws_size,
                              hipStream_t stream)
{
    const void* h  = d_in[0];
    const int*  adj= (const int*)d_in[1];
    const void* W  = d_in[2];
    const void* a  = d_in[3];

    char* ws = (char*)d_ws;
    uint16_t* packed = (uint16_t*)ws;                    // 3,145,728 B
    float* src    = (float*)(ws + 3145728);              // 49,152 B
    float* tgt    = (float*)(ws + 3194880);              // 49,152 B
    float* Mrow   = (float*)(ws + 3244032);              // 49,152 B
    float* Srow   = (float*)(ws + 3293184);              // 49,152 B
    uint32_t* maxtgt = (uint32_t*)(ws + 3342336);        // 64 B
    uint32_t* bm  = (uint32_t*)(ws + 3342464);           // 18,874,368 B
    float* hp     = (float*)(ws + 22216832);             // 4 x 6,291,456 B (total ~45.2 MiB)

    hipMemsetAsync(maxtgt, 0, 4, stream);
    k1_ht  <<<dim3(NN/16),dim3(256), 0, stream>>>(h, W, a, packed, src, tgt, maxtgt);
    k2_mask<<<dim3(NN),   dim3(256), 0, stream>>>(adj, src, maxtgt, tgt, bm, Mrow, Srow);
    k3_pv  <<<dim3(NN/32, JSPLIT), dim3(256), 0, stream>>>(bm, tgt, src, Mrow, Srow,
                                                           packed, h, hp, d_out);
    k4_fin <<<dim3(NN*OUTF/2048), dim3(256), 0, stream>>>(hp, h, d_out);
}